// Round 1
// baseline (2379.287 us; speedup 1.0000x reference)
//
#include <hip/hip_runtime.h>

#define TT 131072
#define NS 64
#define MD 8
#define CHUNK 256
#define NCH 512
#define GRP 8
#define NG 64
#define PSTRIDE 68            // floats per LDS row (272 B, 16B-aligned, breaks write conflicts)
#define PBUF (NS * PSTRIDE)

// log(n!) for n = 0..19  (x in [0,19] per setup_inputs)
__device__ __constant__ float c_lg[20] = {
    0.0f, 0.0f, 0.69314718f, 1.79175947f, 3.17805383f,
    4.78749174f, 6.57925121f, 8.52516136f, 10.60460290f, 12.80182748f,
    15.10441257f, 17.50230785f, 19.98721386f, 22.55216385f, 25.19122118f,
    27.89927138f, 30.67186011f, 33.50507345f, 36.39544521f, 39.33988419f};

// Per-wave emission for time t: lane l = state.
// pe (per-lane) = exp(g - gmax); gshift (uniform) = gmax - sum_m lgamma(x+1)
__device__ __forceinline__ void emission(const int* __restrict__ x, int t,
                                         const float ll[MD], float lamsum,
                                         const float* lgt, float& pe, float& gshift) {
    const int4* xp = (const int4*)(x + (size_t)t * MD);
    int4 xa = xp[0];
    int4 xb = xp[1];
    float g = -lamsum;
    g = fmaf((float)xa.x, ll[0], g);
    g = fmaf((float)xa.y, ll[1], g);
    g = fmaf((float)xa.z, ll[2], g);
    g = fmaf((float)xa.w, ll[3], g);
    g = fmaf((float)xb.x, ll[4], g);
    g = fmaf((float)xb.y, ll[5], g);
    g = fmaf((float)xb.z, ll[6], g);
    g = fmaf((float)xb.w, ll[7], g);
    float Lt = lgt[xa.x] + lgt[xa.y] + lgt[xa.z] + lgt[xa.w] +
               lgt[xb.x] + lgt[xb.y] + lgt[xb.z] + lgt[xb.w];
    float gm = g;
#pragma unroll
    for (int m = 1; m <= 32; m <<= 1) gm = fmaxf(gm, __shfl_xor(gm, m, 64));
    pe = __expf(g - gm);
    gshift = gm - Lt;
}

// ---------------- Kernel B: per-chunk transfer-matrix product ----------------
__global__ __launch_bounds__(256, 2) void k_chunks(
    const int* __restrict__ x, const float* __restrict__ lambdas,
    const float* __restrict__ logT, float* __restrict__ chunkP,
    double* __restrict__ chunkS) {
    __shared__ float P[2][PBUF];
    __shared__ float wmax[2][4];
    __shared__ float lgt[20];
    const int tid = threadIdx.x;
    const int l = tid & 63;   // lane = output row (state i)
    const int w = tid >> 6;   // wave = column block
    const int j0 = w * 16;
    const int c = blockIdx.x;
    const int t0 = 1 + c * CHUNK;
    const int len = min(CHUNK, TT - t0);

    if (tid < 20) lgt[tid] = c_lg[tid];

    float Trow[NS];
#pragma unroll
    for (int k = 0; k < NS; ++k) Trow[k] = __expf(logT[l * NS + k]);

    float ll[MD];
    float lamsum = 0.f;
#pragma unroll
    for (int m = 0; m < MD; ++m) {
        float lam = lambdas[l * MD + m];
        ll[m] = __logf(lam);
        lamsum += lam;
    }
    __syncthreads();  // lgt visible

    // ---- init: P = diag(pe_{t0}) * T ----
    float pe, gs;
    emission(x, t0, ll, lamsum, lgt, pe, gs);
    double S = (double)gs;
    float acc[16];
    {
        const float4* trg = (const float4*)(logT + l * NS + j0);
        float pm = 0.f;
#pragma unroll
        for (int q = 0; q < 4; ++q) {
            float4 tv = trg[q];
            float4 v;
            v.x = pe * __expf(tv.x);
            v.y = pe * __expf(tv.y);
            v.z = pe * __expf(tv.z);
            v.w = pe * __expf(tv.w);
            acc[q * 4 + 0] = v.x;
            acc[q * 4 + 1] = v.y;
            acc[q * 4 + 2] = v.z;
            acc[q * 4 + 3] = v.w;
            *(float4*)(&P[0][l * PSTRIDE + j0 + q * 4]) = v;
            pm = fmaxf(pm, fmaxf(fmaxf(v.x, v.y), fmaxf(v.z, v.w)));
        }
#pragma unroll
        for (int m = 1; m <= 32; m <<= 1) pm = fmaxf(pm, __shfl_xor(pm, m, 64));
        if (l == 0) wmax[0][w] = pm;
    }
    __syncthreads();

    int curp = 0;
#pragma unroll 1
    for (int s = 1; s < len; ++s) {
        const int t = t0 + s;
        emission(x, t, ll, lamsum, lgt, pe, gs);
        const int rp = curp, wp = curp ^ 1;
        float nrm = fmaxf(fmaxf(wmax[rp][0], wmax[rp][1]),
                          fmaxf(wmax[rp][2], wmax[rp][3]));
        float r = 1.0f / nrm;
        S += (double)gs - (double)__logf(r);
        pe *= r;  // fold prev-step rescale into this step's emission
#pragma unroll
        for (int q = 0; q < 16; ++q) acc[q] = 0.f;
        const float* Pb = &P[rp][j0];
#pragma unroll
        for (int k = 0; k < NS; ++k) {
#pragma unroll
            for (int q = 0; q < 4; ++q) {
                float4 p = *(const float4*)(Pb + k * PSTRIDE + q * 4);
                acc[q * 4 + 0] = fmaf(Trow[k], p.x, acc[q * 4 + 0]);
                acc[q * 4 + 1] = fmaf(Trow[k], p.y, acc[q * 4 + 1]);
                acc[q * 4 + 2] = fmaf(Trow[k], p.z, acc[q * 4 + 2]);
                acc[q * 4 + 3] = fmaf(Trow[k], p.w, acc[q * 4 + 3]);
            }
        }
        float pm = 0.f;
#pragma unroll
        for (int q = 0; q < 16; ++q) {
            acc[q] *= pe;
            pm = fmaxf(pm, acc[q]);
        }
#pragma unroll
        for (int m = 1; m <= 32; m <<= 1) pm = fmaxf(pm, __shfl_xor(pm, m, 64));
#pragma unroll
        for (int q = 0; q < 4; ++q)
            *(float4*)(&P[wp][l * PSTRIDE + j0 + q * 4]) =
                make_float4(acc[q * 4 + 0], acc[q * 4 + 1], acc[q * 4 + 2],
                            acc[q * 4 + 3]);
        if (l == 0) wmax[wp][w] = pm;
        __syncthreads();
        curp = wp;
    }
    // ---- epilogue: normalize final P, emit chunk matrix + log-scale ----
    {
        float nrm = fmaxf(fmaxf(wmax[curp][0], wmax[curp][1]),
                          fmaxf(wmax[curp][2], wmax[curp][3]));
        float r = 1.0f / nrm;
        S -= (double)__logf(r);
        float4* out = (float4*)(chunkP + (size_t)c * 4096 + l * 64 + j0);
#pragma unroll
        for (int q = 0; q < 4; ++q)
            out[q] = make_float4(acc[q * 4 + 0] * r, acc[q * 4 + 1] * r,
                                 acc[q * 4 + 2] * r, acc[q * 4 + 3] * r);
        if (tid == 0) chunkS[c] = S;
    }
}

// ---------------- Kernel C1: combine 8 chunk matrices -> 1 group matrix ------
__global__ __launch_bounds__(256, 2) void k_combine(
    const float* __restrict__ chunkP, const double* __restrict__ chunkS,
    float* __restrict__ Q, double* __restrict__ QS) {
    __shared__ float R[2][PBUF];
    __shared__ float wmax[2][4];
    const int tid = threadIdx.x;
    const int l = tid & 63;
    const int w = tid >> 6;
    const int j0 = w * 16;
    const int g = blockIdx.x;
    const int c0 = g * GRP;

    float acc[16];
    {
        const float4* src =
            (const float4*)(chunkP + (size_t)c0 * 4096 + l * 64 + j0);
#pragma unroll
        for (int q = 0; q < 4; ++q) {
            float4 v = src[q];
            acc[q * 4 + 0] = v.x;
            acc[q * 4 + 1] = v.y;
            acc[q * 4 + 2] = v.z;
            acc[q * 4 + 3] = v.w;
            *(float4*)(&R[0][l * PSTRIDE + j0 + q * 4]) = v;
        }
    }
    double S = chunkS[c0];
    __syncthreads();

#pragma unroll 1
    for (int n = 1; n < GRP; ++n) {
        const int rp = (n - 1) & 1, wp = n & 1;
        float Arow[NS];
        {
            const float4* ap =
                (const float4*)(chunkP + (size_t)(c0 + n) * 4096 + l * 64);
#pragma unroll
            for (int q = 0; q < 16; ++q) {
                float4 v = ap[q];
                Arow[q * 4 + 0] = v.x;
                Arow[q * 4 + 1] = v.y;
                Arow[q * 4 + 2] = v.z;
                Arow[q * 4 + 3] = v.w;
            }
        }
        if (n > 1) {
            float nrm = fmaxf(fmaxf(wmax[rp][0], wmax[rp][1]),
                              fmaxf(wmax[rp][2], wmax[rp][3]));
            float r = 1.0f / nrm;
            S -= (double)__logf(r);
#pragma unroll
            for (int k = 0; k < NS; ++k) Arow[k] *= r;
        }
        S += chunkS[c0 + n];
#pragma unroll
        for (int q = 0; q < 16; ++q) acc[q] = 0.f;
        const float* Rb = &R[rp][j0];
#pragma unroll
        for (int k = 0; k < NS; ++k) {
#pragma unroll
            for (int q = 0; q < 4; ++q) {
                float4 p = *(const float4*)(Rb + k * PSTRIDE + q * 4);
                acc[q * 4 + 0] = fmaf(Arow[k], p.x, acc[q * 4 + 0]);
                acc[q * 4 + 1] = fmaf(Arow[k], p.y, acc[q * 4 + 1]);
                acc[q * 4 + 2] = fmaf(Arow[k], p.z, acc[q * 4 + 2]);
                acc[q * 4 + 3] = fmaf(Arow[k], p.w, acc[q * 4 + 3]);
            }
        }
        float pm = 0.f;
#pragma unroll
        for (int q = 0; q < 16; ++q) pm = fmaxf(pm, acc[q]);
#pragma unroll
        for (int m = 1; m <= 32; m <<= 1) pm = fmaxf(pm, __shfl_xor(pm, m, 64));
#pragma unroll
        for (int q = 0; q < 4; ++q)
            *(float4*)(&R[wp][l * PSTRIDE + j0 + q * 4]) =
                make_float4(acc[q * 4 + 0], acc[q * 4 + 1], acc[q * 4 + 2],
                            acc[q * 4 + 3]);
        if (l == 0) wmax[wp][w] = pm;
        __syncthreads();
    }
    {
        const int fp = (GRP - 1) & 1;
        float nrm = fmaxf(fmaxf(wmax[fp][0], wmax[fp][1]),
                          fmaxf(wmax[fp][2], wmax[fp][3]));
        float r = 1.0f / nrm;
        S -= (double)__logf(r);
        float4* out = (float4*)(Q + (size_t)g * 4096 + l * 64 + j0);
#pragma unroll
        for (int q = 0; q < 4; ++q)
            out[q] = make_float4(acc[q * 4 + 0] * r, acc[q * 4 + 1] * r,
                                 acc[q * 4 + 2] * r, acc[q * 4 + 3] * r);
        if (tid == 0) QS[g] = S;
    }
}

// ---------------- Kernel C2: alpha0 through 64 group matrices + final LSE ----
__global__ void k_final(const int* __restrict__ x,
                        const float* __restrict__ lambdas,
                        const float* __restrict__ prior,
                        const float* __restrict__ Q,
                        const double* __restrict__ QS,
                        float* __restrict__ out) {
    __shared__ __align__(16) float alpha[NS];
    __shared__ float lgt[20];
    const int i = threadIdx.x;  // 0..63, one wave
    if (i < 20) lgt[i] = c_lg[i];
    float ll[MD];
    float lamsum = 0.f;
#pragma unroll
    for (int m = 0; m < MD; ++m) {
        float lam = lambdas[i * MD + m];
        ll[m] = __logf(lam);
        lamsum += lam;
    }
    __syncthreads();
    float pe, gs;
    emission(x, 0, ll, lamsum, lgt, pe, gs);
    double S = (double)gs;
    float a = pe * __expf(prior[i]);
    alpha[i] = a;
    __syncthreads();

    float acc = a;
#pragma unroll 1
    for (int g = 0; g < NG; ++g) {
        float Qrow[NS];
        const float4* qp = (const float4*)(Q + (size_t)g * 4096 + i * 64);
#pragma unroll
        for (int q = 0; q < 16; ++q) {
            float4 v = qp[q];
            Qrow[q * 4 + 0] = v.x;
            Qrow[q * 4 + 1] = v.y;
            Qrow[q * 4 + 2] = v.z;
            Qrow[q * 4 + 3] = v.w;
        }
        float av[NS];
        const float4* apx = (const float4*)alpha;
#pragma unroll
        for (int q = 0; q < 16; ++q) {
            float4 v = apx[q];
            av[q * 4 + 0] = v.x;
            av[q * 4 + 1] = v.y;
            av[q * 4 + 2] = v.z;
            av[q * 4 + 3] = v.w;
        }
        float a0 = 0.f, a1 = 0.f, a2 = 0.f, a3 = 0.f;
#pragma unroll
        for (int k = 0; k < NS; k += 4) {
            a0 = fmaf(Qrow[k + 0], av[k + 0], a0);
            a1 = fmaf(Qrow[k + 1], av[k + 1], a1);
            a2 = fmaf(Qrow[k + 2], av[k + 2], a2);
            a3 = fmaf(Qrow[k + 3], av[k + 3], a3);
        }
        acc = (a0 + a1) + (a2 + a3);
        S += QS[g];
        float pm = acc;
#pragma unroll
        for (int m = 1; m <= 32; m <<= 1) pm = fmaxf(pm, __shfl_xor(pm, m, 64));
        float r = 1.0f / pm;
        acc *= r;
        S -= (double)__logf(r);
        __syncthreads();
        alpha[i] = acc;
        __syncthreads();
    }
    float ssum = acc;
#pragma unroll
    for (int m = 1; m <= 32; m <<= 1) ssum += __shfl_xor(ssum, m, 64);
    if (i == 0) out[0] = (float)(S + (double)__logf(ssum));
}

extern "C" void kernel_launch(void* const* d_in, const int* in_sizes, int n_in,
                              void* d_out, int out_size, void* d_ws,
                              size_t ws_size, hipStream_t stream) {
    const int* x = (const int*)d_in[0];
    const float* lambdas = (const float*)d_in[1];
    const float* logT = (const float*)d_in[2];
    const float* prior = (const float*)d_in[3];
    float* out = (float*)d_out;
    char* ws = (char*)d_ws;
    // ws layout (≈9.44 MB total):
    float* chunkP = (float*)ws;                    // 512*4096*4 = 8388608
    double* chunkS = (double*)(ws + 8388608);      // 512*8     = 4096
    float* Q = (float*)(ws + 8392704);             // 64*4096*4 = 1048576
    double* QS = (double*)(ws + 9441280);          // 64*8      = 512

    k_chunks<<<NCH, 256, 0, stream>>>(x, lambdas, logT, chunkP, chunkS);
    k_combine<<<NG, 256, 0, stream>>>(chunkP, chunkS, Q, QS);
    k_final<<<1, 64, 0, stream>>>(x, lambdas, prior, Q, QS, out);
}

// Round 4
// 170.987 us; speedup vs baseline: 13.9150x; 13.9150x over previous
//
#include <hip/hip_runtime.h>
#include <stdint.h>

#define TT 131072
#define MD 8
#define CHUNK 64
#define RMP 72   // row-major LDS pad (shorts per row)
#define CMP 80   // col-major LDS pad (shorts per col)

using f32x4  = __attribute__((ext_vector_type(4))) float;
using bf16x8 = __attribute__((ext_vector_type(8))) __bf16;
using u32x2  = __attribute__((ext_vector_type(2))) uint32_t;
using u32x4  = __attribute__((ext_vector_type(4))) uint32_t;

// log(n!) for n = 0..19 (x in [0,20))
__device__ __constant__ float c_lg[20] = {
    0.0f, 0.0f, 0.69314718f, 1.79175947f, 3.17805383f,
    4.78749174f, 6.57925121f, 8.52516136f, 10.60460290f, 12.80182748f,
    15.10441257f, 17.50230785f, 19.98721386f, 22.55216385f, 25.19122118f,
    27.89927138f, 30.67186011f, 33.50507345f, 36.39544521f, 39.33988419f};

#define MFMA(a, b, c) __builtin_amdgcn_mfma_f32_16x16x32_bf16((a), (b), (c), 0, 0, 0)

// Bookkeeping fragment map sigma (consistent everywhere; HW map may differ —
// it cancels): frag elem e of a K=32 operand covers k = 16*(e>>2) + 4*q + (e&3),
// with q = lane>>4; A rows / B cols on lane&15. State B[kf][nb] holds
// M[32kf + sigma(l,e)][16nb + (l&15)].

// emission: lane = state. pe = exp(g-gmax), gs = gmax - sum lgamma(x+1)
__device__ __forceinline__ void emis(const int4& xa, const int4& xb,
                                     const float* ll, float lamsum,
                                     const float* lgt, float& pe, float& gs) {
    float g = -lamsum;
    g = fmaf((float)xa.x, ll[0], g);
    g = fmaf((float)xa.y, ll[1], g);
    g = fmaf((float)xa.z, ll[2], g);
    g = fmaf((float)xa.w, ll[3], g);
    g = fmaf((float)xb.x, ll[4], g);
    g = fmaf((float)xb.y, ll[5], g);
    g = fmaf((float)xb.z, ll[6], g);
    g = fmaf((float)xb.w, ll[7], g);
    float Lt = lgt[xa.x] + lgt[xa.y] + lgt[xa.z] + lgt[xa.w] +
               lgt[xb.x] + lgt[xb.y] + lgt[xb.z] + lgt[xb.w];
    float gm = g;
#pragma unroll
    for (int m = 1; m <= 32; m <<= 1) gm = fmaxf(gm, __shfl_xor(gm, m, 64));
    pe = __expf(g - gm);
    gs = gm - Lt;
}

// ---- fragment <-> memory helpers (all use map sigma) ----

// scatter state regs -> LDS row-major [k][n] pad RMP
__device__ __forceinline__ void state_to_rm(short* rm, const bf16x8 B[2][4],
                                            int li, int q) {
#pragma unroll
    for (int kf = 0; kf < 2; ++kf)
#pragma unroll
        for (int nb = 0; nb < 4; ++nb) {
            u32x4 u = __builtin_bit_cast(u32x4, B[kf][nb]);
            int n = 16 * nb + li;
#pragma unroll
            for (int wi = 0; wi < 4; ++wi) {
                int k0 = 32 * kf + 16 * (wi >> 1) + 4 * q + 2 * (wi & 1);
                uint32_t v = u[wi];
                rm[k0 * RMP + n] = (short)(v & 0xFFFFu);
                rm[(k0 + 1) * RMP + n] = (short)(v >> 16);
            }
        }
}

// read A-frags of matrix in LDS row-major [m][k] pad RMP
__device__ __forceinline__ void load_afrags(const short* rm, int li, int q,
                                            bf16x8 A[4][2]) {
#pragma unroll
    for (int mb = 0; mb < 4; ++mb)
#pragma unroll
        for (int kf = 0; kf < 2; ++kf) {
            const short* p = rm + (16 * mb + li) * RMP + 32 * kf + 4 * q;
            u32x2 lo = *(const u32x2*)p;
            u32x2 hi = *(const u32x2*)(p + 16);
            u32x4 u = {lo[0], lo[1], hi[0], hi[1]};
            A[mb][kf] = __builtin_bit_cast(bf16x8, u);
        }
}

// state regs -> LDS col-major [n][k] pad CMP (k-consecutive u32 writes)
__device__ __forceinline__ void state_to_cm(short* cm, const bf16x8 B[2][4],
                                            int li, int q) {
#pragma unroll
    for (int kf = 0; kf < 2; ++kf)
#pragma unroll
        for (int nb = 0; nb < 4; ++nb) {
            u32x4 u = __builtin_bit_cast(u32x4, B[kf][nb]);
            int n = 16 * nb + li;
#pragma unroll
            for (int wi = 0; wi < 4; ++wi) {
                int k0 = 32 * kf + 16 * (wi >> 1) + 4 * q + 2 * (wi & 1);
                *(uint32_t*)&cm[n * CMP + k0] = u[wi];
            }
        }
}

// load state B-frags from global col-major dump (addr = n*64 + k shorts)
__device__ __forceinline__ void load_state_global(const short* gm,
                                                  bf16x8 B[2][4], int li,
                                                  int q) {
#pragma unroll
    for (int kf = 0; kf < 2; ++kf)
#pragma unroll
        for (int nb = 0; nb < 4; ++nb) {
            const short* p = gm + (16 * nb + li) * 64 + 32 * kf + 4 * q;
            u32x2 v0 = *(const u32x2*)p;
            u32x2 v1 = *(const u32x2*)(p + 16);
            u32x4 u = {v0[0], v0[1], v1[0], v1[1]};
            B[kf][nb] = __builtin_bit_cast(bf16x8, u);
        }
}

// B <- normalize(A*B); returns pm (pre-scale max). Exact log bookkeeping by caller.
__device__ __forceinline__ float leftmul(const bf16x8 A[4][2], bf16x8 B[2][4]) {
    f32x4 d[4][4];
#pragma unroll
    for (int mb = 0; mb < 4; ++mb)
#pragma unroll
        for (int nb = 0; nb < 4; ++nb) {
            f32x4 z = {0.f, 0.f, 0.f, 0.f};
            d[mb][nb] = MFMA(A[mb][0], B[0][nb], z);
            d[mb][nb] = MFMA(A[mb][1], B[1][nb], d[mb][nb]);
        }
    float pm = 0.f;
#pragma unroll
    for (int mb = 0; mb < 4; ++mb)
#pragma unroll
        for (int nb = 0; nb < 4; ++nb)
            pm = fmaxf(pm, fmaxf(fmaxf(d[mb][nb][0], d[mb][nb][1]),
                                 fmaxf(d[mb][nb][2], d[mb][nb][3])));
#pragma unroll
    for (int m = 1; m <= 32; m <<= 1) pm = fmaxf(pm, __shfl_xor(pm, m, 64));
    pm = fmaxf(pm, 1e-30f);
    float r = 1.0f / pm;
#pragma unroll
    for (int mb = 0; mb < 4; ++mb)
#pragma unroll
        for (int nb = 0; nb < 4; ++nb) {
#pragma unroll
            for (int reg = 0; reg < 4; ++reg)
                B[mb >> 1][nb][(mb & 1) * 4 + reg] =
                    (__bf16)(d[mb][nb][reg] * r);
        }
    return pm;
}

// ---------------- K1: per-chunk transfer-matrix product, in-register --------
__global__ __launch_bounds__(256, 2) void k_chunks(
    const int* __restrict__ x, const float* __restrict__ lambdas,
    const float* __restrict__ logT, short* __restrict__ M1,
    double* __restrict__ S1) {
    __shared__ short rm[4][64 * RMP];
    __shared__ short cm[64 * CMP];
    __shared__ float lgt[20];
    __shared__ double Sw[4];
    __shared__ double SwT;
    const int tid = threadIdx.x;
    const int l = tid & 63, w = tid >> 6;
    const int li = l & 15, q = l >> 4;
    if (tid < 20) lgt[tid] = c_lg[tid];

    // emission constants (lane = state)
    float ll[8];
    float lamsum = 0.f;
#pragma unroll
    for (int m = 0; m < 8; ++m) {
        float lam = lambdas[l * 8 + m];
        ll[m] = __logf(lam);
        lamsum += lam;
    }

    // constant A-frags of T: elem e of TA[mb][kf] = T[16mb+li][32kf+sigma(l,e)]
    bf16x8 TA[4][2];
#pragma unroll
    for (int mb = 0; mb < 4; ++mb)
#pragma unroll
        for (int kf = 0; kf < 2; ++kf) {
            const float* tp = logT + (16 * mb + li) * 64 + 32 * kf + 4 * q;
            float4 v0 = *(const float4*)tp;
            float4 v1 = *(const float4*)(tp + 16);
            bf16x8 a;
            a[0] = (__bf16)__expf(v0.x);
            a[1] = (__bf16)__expf(v0.y);
            a[2] = (__bf16)__expf(v0.z);
            a[3] = (__bf16)__expf(v0.w);
            a[4] = (__bf16)__expf(v1.x);
            a[5] = (__bf16)__expf(v1.y);
            a[6] = (__bf16)__expf(v1.z);
            a[7] = (__bf16)__expf(v1.w);
            TA[mb][kf] = a;
        }

    // state = Identity (B-frag format, map sigma)
    bf16x8 B[2][4];
#pragma unroll
    for (int kf = 0; kf < 2; ++kf)
#pragma unroll
        for (int nb = 0; nb < 4; ++nb) {
            int n = 16 * nb + li;
            u32x4 u;
#pragma unroll
            for (int wi = 0; wi < 4; ++wi) {
                int k0 = 32 * kf + 16 * (wi >> 1) + 4 * q + 2 * (wi & 1);
                uint32_t v = 0;
                if (k0 == n) v |= 0x3F80u;
                if (k0 + 1 == n) v |= 0x3F800000u;
                u[wi] = v;
            }
            B[kf][nb] = __builtin_bit_cast(bf16x8, u);
        }
    __syncthreads();  // lgt visible

    const int c = blockIdx.x * 4 + w;
    const int t0 = 1 + c * CHUNK;
    const int len = min(CHUNK, TT - t0);

    double S = 0.0;
    float nrm = 1.0f;
    int4 xa = *(const int4*)(x + (size_t)t0 * MD);
    int4 xb = *(const int4*)(x + (size_t)t0 * MD + 4);

#pragma unroll 1
    for (int s = 0; s < len; ++s) {
        int tn = t0 + s + 1;
        if (tn > TT - 1) tn = TT - 1;
        int4 xan = *(const int4*)(x + (size_t)tn * MD);
        int4 xbn = *(const int4*)(x + (size_t)tn * MD + 4);

        float pe, gs;
        emis(xa, xb, ll, lamsum, lgt, pe, gs);
        float r = 1.0f / nrm;           // stale-max rescale (exact bookkeeping)
        S += (double)gs + (double)__logf(nrm);
        float per = pe * r;

        float pm = 0.f;
        bf16x8 nB[2][4];
#pragma unroll
        for (int mb = 0; mb < 4; ++mb) {
            f32x4 d[4];
#pragma unroll
            for (int nb = 0; nb < 4; ++nb) {
                f32x4 z = {0.f, 0.f, 0.f, 0.f};
                d[nb] = MFMA(TA[mb][0], B[0][nb], z);
                d[nb] = MFMA(TA[mb][1], B[1][nb], d[nb]);
            }
            // emission row-scale: rows of this mb-tile = 16mb + 4q + reg
            float sc0 = __shfl(per, 16 * mb + 4 * q + 0, 64);
            float sc1 = __shfl(per, 16 * mb + 4 * q + 1, 64);
            float sc2 = __shfl(per, 16 * mb + 4 * q + 2, 64);
            float sc3 = __shfl(per, 16 * mb + 4 * q + 3, 64);
#pragma unroll
            for (int nb = 0; nb < 4; ++nb) {
                float v0 = d[nb][0] * sc0;
                float v1 = d[nb][1] * sc1;
                float v2 = d[nb][2] * sc2;
                float v3 = d[nb][3] * sc3;
                pm = fmaxf(pm, fmaxf(fmaxf(v0, v1), fmaxf(v2, v3)));
                nB[mb >> 1][nb][(mb & 1) * 4 + 0] = (__bf16)v0;
                nB[mb >> 1][nb][(mb & 1) * 4 + 1] = (__bf16)v1;
                nB[mb >> 1][nb][(mb & 1) * 4 + 2] = (__bf16)v2;
                nB[mb >> 1][nb][(mb & 1) * 4 + 3] = (__bf16)v3;
            }
        }
#pragma unroll
        for (int m = 1; m <= 32; m <<= 1) pm = fmaxf(pm, __shfl_xor(pm, m, 64));
        nrm = fmaxf(pm, 1e-30f);
#pragma unroll
        for (int kf = 0; kf < 2; ++kf)
#pragma unroll
            for (int nb = 0; nb < 4; ++nb) B[kf][nb] = nB[kf][nb];
        xa = xan;
        xb = xbn;
    }

    // ---- block combine: product = S3*S2*S1*S0 ----
    if (w) state_to_rm(&rm[w][0], B, li, q);
    if (l == 0) Sw[w] = S;
    __syncthreads();
    if (w == 0) {
#pragma unroll 1
        for (int j = 1; j < 4; ++j) {
            bf16x8 A[4][2];
            load_afrags(&rm[j][0], li, q, A);
            float pm = leftmul(A, B);
            S += Sw[j] + (double)__logf(pm);
        }
        state_to_cm(cm, B, li, q);
        if (l == 0) SwT = S;
    }
    __syncthreads();
    {
        short* gm = M1 + (size_t)blockIdx.x * 4096;
        int n = tid >> 2, cc = tid & 3;
        *(u32x4*)(gm + n * 64 + cc * 8) = *(const u32x4*)&cm[n * CMP + cc * 8];
        *(u32x4*)(gm + n * 64 + 32 + cc * 8) =
            *(const u32x4*)&cm[n * CMP + 32 + cc * 8];
        if (tid == 0) S1[blockIdx.x] = SwT;
    }
}

// ---------------- K2: fold 512 -> 8 ----------------------------------------
__global__ __launch_bounds__(256, 1) void k_combine(
    const short* __restrict__ M1, const double* __restrict__ S1,
    short* __restrict__ M2, double* __restrict__ S2) {
    __shared__ short rm[4][64 * RMP];
    __shared__ short cm[64 * CMP];
    __shared__ double Sw[4];
    __shared__ double SwT;
    const int tid = threadIdx.x;
    const int l = tid & 63, w = tid >> 6;
    const int li = l & 15, q = l >> 4;
    const int base = blockIdx.x * 64 + w * 16;

    bf16x8 B[2][4];
    load_state_global(M1 + (size_t)base * 4096, B, li, q);
    double S = S1[base];

#pragma unroll 1
    for (int j = 1; j < 16; ++j) {
        const short* gm = M1 + (size_t)(base + j) * 4096;
        // stage col-major global -> row-major LDS (lane covers column l)
#pragma unroll
        for (int ch = 0; ch < 8; ++ch) {
            u32x4 v = *(const u32x4*)(gm + l * 64 + ch * 8);
            short* dst = &rm[w][0];
#pragma unroll
            for (int e = 0; e < 4; ++e) {
                uint32_t u = v[e];
                dst[(ch * 8 + 2 * e) * RMP + l] = (short)(u & 0xFFFFu);
                dst[(ch * 8 + 2 * e + 1) * RMP + l] = (short)(u >> 16);
            }
        }
        __syncthreads();
        bf16x8 A[4][2];
        load_afrags(&rm[w][0], li, q, A);
        float pm = leftmul(A, B);
        S += S1[base + j] + (double)__logf(pm);
        __syncthreads();
    }

    if (w) state_to_rm(&rm[w][0], B, li, q);
    if (l == 0) Sw[w] = S;
    __syncthreads();
    if (w == 0) {
#pragma unroll 1
        for (int j = 1; j < 4; ++j) {
            bf16x8 A[4][2];
            load_afrags(&rm[j][0], li, q, A);
            float pm = leftmul(A, B);
            S += Sw[j] + (double)__logf(pm);
        }
        state_to_cm(cm, B, li, q);
        if (l == 0) SwT = S;
    }
    __syncthreads();
    {
        short* gm = M2 + (size_t)blockIdx.x * 4096;
        int n = tid >> 2, cc = tid & 3;
        *(u32x4*)(gm + n * 64 + cc * 8) = *(const u32x4*)&cm[n * CMP + cc * 8];
        *(u32x4*)(gm + n * 64 + 32 + cc * 8) =
            *(const u32x4*)&cm[n * CMP + 32 + cc * 8];
        if (tid == 0) S2[blockIdx.x] = SwT;
    }
}

// ---------------- K3: fold 8 -> 1, alpha0, final LSE ------------------------
__global__ __launch_bounds__(64, 1) void k_final(
    const int* __restrict__ x, const float* __restrict__ lambdas,
    const float* __restrict__ prior, const short* __restrict__ M2,
    const double* __restrict__ S2, float* __restrict__ out) {
    __shared__ short rm[64 * RMP];
    __shared__ float lgt[20];
    const int l = threadIdx.x;
    const int li = l & 15, q = l >> 4;
    if (l < 20) lgt[l] = c_lg[l];
    __syncthreads();

    bf16x8 B[2][4];
    load_state_global(M2, B, li, q);
    double S = S2[0];

#pragma unroll 1
    for (int j = 1; j < 8; ++j) {
        const short* gm = M2 + (size_t)j * 4096;
#pragma unroll
        for (int ch = 0; ch < 8; ++ch) {
            u32x4 v = *(const u32x4*)(gm + l * 64 + ch * 8);
#pragma unroll
            for (int e = 0; e < 4; ++e) {
                uint32_t u = v[e];
                rm[(ch * 8 + 2 * e) * RMP + l] = (short)(u & 0xFFFFu);
                rm[(ch * 8 + 2 * e + 1) * RMP + l] = (short)(u >> 16);
            }
        }
        __syncthreads();
        bf16x8 A[4][2];
        load_afrags(rm, li, q, A);
        float pm = leftmul(A, B);
        S += S2[j] + (double)__logf(pm);
        __syncthreads();
    }

    // alpha0 = pe0 * exp(prior), S += gs0
    float ll[8];
    float lamsum = 0.f;
#pragma unroll
    for (int m = 0; m < 8; ++m) {
        float lam = lambdas[l * 8 + m];
        ll[m] = __logf(lam);
        lamsum += lam;
    }
    int4 xa = *(const int4*)(x);
    int4 xb = *(const int4*)(x + 4);
    float pe0, gs0;
    emis(xa, xb, ll, lamsum, lgt, pe0, gs0);
    S += (double)gs0;
    float a0 = pe0 * __expf(prior[l]);

    float av[4];
#pragma unroll
    for (int nb = 0; nb < 4; ++nb) av[nb] = __shfl(a0, 16 * nb + li, 64);

    // total = 1^T * M * a0 : each (k,n) element appears exactly once across slots
    float acc = 0.f;
#pragma unroll
    for (int kf = 0; kf < 2; ++kf)
#pragma unroll
        for (int nb = 0; nb < 4; ++nb) {
            u32x4 u = __builtin_bit_cast(u32x4, B[kf][nb]);
#pragma unroll
            for (int e = 0; e < 4; ++e) {
                float flo = __builtin_bit_cast(float, u[e] << 16);
                float fhi = __builtin_bit_cast(float, u[e] & 0xFFFF0000u);
                acc = fmaf(flo + fhi, av[nb], acc);
            }
        }
#pragma unroll
    for (int m = 1; m <= 32; m <<= 1) acc += __shfl_xor(acc, m, 64);
    if (l == 0) out[0] = (float)(S + (double)__logf(acc));
}

extern "C" void kernel_launch(void* const* d_in, const int* in_sizes, int n_in,
                              void* d_out, int out_size, void* d_ws,
                              size_t ws_size, hipStream_t stream) {
    const int* x = (const int*)d_in[0];
    const float* lambdas = (const float*)d_in[1];
    const float* logT = (const float*)d_in[2];
    const float* prior = (const float*)d_in[3];
    float* out = (float*)d_out;
    char* ws = (char*)d_ws;
    // ws layout (~4.27 MB): M1 512*4096*2B, S1 512*8B, M2 8*4096*2B, S2 8*8B
    short* M1 = (short*)ws;
    double* S1 = (double*)(ws + 4194304);
    short* M2 = (short*)(ws + 4198400);
    double* S2 = (double*)(ws + 4263936);

    k_chunks<<<512, 256, 0, stream>>>(x, lambdas, logT, M1, S1);
    k_combine<<<8, 256, 0, stream>>>(M1, S1, M2, S2);
    k_final<<<1, 64, 0, stream>>>(x, lambdas, prior, M2, S2, out);
}